// Round 6
// baseline (464.634 us; speedup 1.0000x reference)
//
#include <hip/hip_runtime.h>

typedef _Float16 f16;
typedef _Float16 f16x4 __attribute__((ext_vector_type(4)));
typedef _Float16 f16x8 __attribute__((ext_vector_type(8)));
typedef float f32x4 __attribute__((ext_vector_type(4)));

// ---- f16 weight arena layout in d_ws (units: halfs) ----
#define OFF_W1  0            // s1_w *30   [128][64]
#define OFF_W2  8192         // s2_w *30   [256][128]
#define OFF_WF1 40960        // fc1_w      [64][256]
#define OFF_WF2 57344        // fc2_w      [64][64]
#define OFF_WF3 61440        // fc3_w      [256][64]
#define OFF_WGE 77824        // [16][288]: rows 0..6 gate_w, 8..14 exp_w (cols<256), rest 0
#define OFF_WP2 82432        // p2_w *30   [32][32]
#define TOTH    83456
// ---- fp32 bias arena at (float*)(ws + TOTH), units: floats ----
#define FB_B1  0             // 30*s1_b (128)
#define FB_B2  128           // 30*s2_b (256)
#define FB_F1  384           // fc1_b (64)
#define FB_F2  448           // fc2_b (64)
#define FB_F3  512           // fc3_b (256)
#define FB_GE  768           // gate_b(0..6), 0, exp_b(8..14), 0
#define FB_P2  784           // 30*p2_b (32)

// sin(x): v_sin_f32 takes revolutions, 1-periodic -> fract is a valid reduction.
__device__ __forceinline__ float fsin(float x){
  return __builtin_amdgcn_sinf(__builtin_amdgcn_fractf(x * 0.15915494309189535f));
}
__device__ __forceinline__ float fcos(float x){
  return __builtin_amdgcn_sinf(__builtin_amdgcn_fractf(
      fmaf(x, 0.15915494309189535f, 0.25f)));
}

// ---------- weight conversion: fp32 -> f16, OMEGA folded ----------
__global__ void convert_w(const float* __restrict__ s1w, const float* __restrict__ s1b,
                          const float* __restrict__ s2w, const float* __restrict__ s2b,
                          const float* __restrict__ f1w, const float* __restrict__ f1b,
                          const float* __restrict__ f2w, const float* __restrict__ f2b,
                          const float* __restrict__ f3w, const float* __restrict__ f3b,
                          const float* __restrict__ gw,  const float* __restrict__ gb,
                          const float* __restrict__ ew,  const float* __restrict__ eb,
                          const float* __restrict__ p2w, const float* __restrict__ p2b,
                          f16* __restrict__ ws)
{
  int stride = gridDim.x * blockDim.x;
  int tid0 = blockIdx.x * blockDim.x + threadIdx.x;
  for (int i = tid0; i < TOTH; i += stride){
    float v;
    if (i < OFF_W2)       v = 30.0f * s1w[i];
    else if (i < OFF_WF1) v = 30.0f * s2w[i - OFF_W2];
    else if (i < OFF_WF2) v = f1w[i - OFF_WF1];
    else if (i < OFF_WF3) v = f2w[i - OFF_WF2];
    else if (i < OFF_WGE) v = f3w[i - OFF_WF3];
    else if (i < OFF_WP2){
      int j = i - OFF_WGE; int row = j / 288; int col = j - row * 288;
      v = (row < 7) ? gw[row * 288 + col]
        : ((row >= 8 && row < 15 && col < 256) ? ew[(row - 8) * 256 + col] : 0.0f);
    }
    else v = 30.0f * p2w[i - OFF_WP2];
    ws[i] = (f16)v;
  }
  float* bws = (float*)(ws + TOTH);
  for (int i = tid0; i < 816; i += stride){
    float v;
    if (i < 128)      v = 30.0f * s1b[i];
    else if (i < 384) v = 30.0f * s2b[i - 128];
    else if (i < 448) v = f1b[i - 384];
    else if (i < 512) v = f2b[i - 448];
    else if (i < 768) v = f3b[i - 512];
    else if (i < 784){ int j = i - 768;
      v = (j < 7) ? gb[j] : ((j >= 8 && j < 15) ? eb[j - 8] : 0.0f); }
    else v = 30.0f * p2b[i - 784];
    bws[i] = v;
  }
}

// Index helpers (offsets in halfs). IDXS: XOR-swizzle 16B granules within a row.
#define IDXP(r_, c_, S_) ((r_) * (S_) + (c_))
#define IDXS(r_, c_, S_) ((r_) * (S_) + (((((c_) >> 3) ^ ((r_) & 7)) << 3) | ((c_) & 7)))

#define STORE4(P_, S_, IDX_, E0_, E1_, E2_, E3_)                                     \
  { f16x4 o; o[0] = (f16)(E0_); o[1] = (f16)(E1_); o[2] = (f16)(E2_); o[3] = (f16)(E3_); \
    *(f16x4*)((P_) + IDX_(r, n0, S_)) = o; }

// Swapped-operand layer pass over a 64-row block. Wave handles NCT_ ct-tiles
// (ct via CTEXPR_ over jj) x NRT_ row-tiles from RT0_. Bias folded into MFMA C-in.
// Per-layer splits chosen so af[NRT][K/32] + acc + wv stay under the 85-VGPR cap
// (launch_bounds(512,6)): R5's af[4][4]/af[2][8] spilled 139MB to scratch.
#define MM_LAYER(K_, ACT_, SA_, AIDX_, NCT_, CTEXPR_, RT0_, NRT_, WOFF_, BOFF_, ...) \
  {                                                                                  \
    f16x8 af[NRT_][(K_) / 32];                                                       \
    _Pragma("unroll")                                                                \
    for (int rr = 0; rr < (NRT_); ++rr)                                              \
      _Pragma("unroll")                                                              \
      for (int ks = 0; ks < (K_) / 32; ++ks)                                         \
        af[rr][ks] = *(const f16x8*)((ACT_) +                                        \
                       AIDX_((((RT0_) + rr) * 16 + l15), (ks * 32 + kb), (SA_)));    \
    _Pragma("unroll")                                                                \
    for (int jj = 0; jj < (NCT_); ++jj){                                             \
      const int ct = (CTEXPR_);                                                      \
      float4 bias = *(const float4*)(bws + (BOFF_) + ct * 16 + lk * 4);              \
      f32x4 acc[NRT_];                                                               \
      _Pragma("unroll")                                                              \
      for (int rr = 0; rr < (NRT_); ++rr)                                            \
        acc[rr] = (f32x4){bias.x, bias.y, bias.z, bias.w};                           \
      _Pragma("unroll")                                                              \
      for (int ks = 0; ks < (K_) / 32; ++ks){                                        \
        f16x8 wv = *(const f16x8*)(ws + (WOFF_) + (ct * 16 + l15) * (K_) + ks * 32 + kb); \
        _Pragma("unroll")                                                            \
        for (int rr = 0; rr < (NRT_); ++rr)                                          \
          acc[rr] = __builtin_amdgcn_mfma_f32_16x16x32_f16(wv, af[rr][ks], acc[rr], 0, 0, 0); \
      }                                                                              \
      _Pragma("unroll")                                                              \
      for (int rr = 0; rr < (NRT_); ++rr){                                           \
        const int r = ((RT0_) + rr) * 16 + l15;                                      \
        const int n0 = ct * 16 + lk * 4;                                             \
        float v0 = acc[rr][0], v1 = acc[rr][1], v2 = acc[rr][2], v3 = acc[rr][3];    \
        __VA_ARGS__;                                                                 \
      }                                                                              \
    }                                                                                \
  }                                                                                  \
  __syncthreads();

__global__ __launch_bounds__(512, 6) void moe_main(
    const float* __restrict__ x,
    const float* __restrict__ pe_w, const float* __restrict__ pe_b,
    const float* __restrict__ p1_w, const float* __restrict__ p1_b,
    const f16* __restrict__ ws, float* __restrict__ out)
{
  const float* bws = (const float*)(ws + TOTH);
  // 53248 B = 160KiB/3 -> 3 blocks/CU. Lifetime-packed overlays:
  //  Z [0,32768):   h0 [64][72] + f1 [64][40] (pre-barrier-B)  ->  h2 [64][256] swz (s2..end)
  //  Y [32768,49152): h1 [64][128] swz (s1..s2)  ->  t1 [64][64] swz + t2 [64][64] swz
  //  F2 [49152,53248): f2 [64][32] (p2..gate)
  __shared__ __align__(16) unsigned char smem[53248];
  f16* h2 = (f16*)smem;                  // [64][256] swizzled
  f16* h0 = (f16*)smem;                  // [64][72]  plain (dead at barrier B)
  f16* f1 = (f16*)(smem + 9216);         // [64][40]  plain (dead at barrier B)
  f16* h1 = (f16*)(smem + 32768);        // [64][128] swizzled (dead at barrier C)
  f16* t1 = (f16*)(smem + 32768);        // [64][64]  swizzled (fc1 -> fc2)
  f16* t2 = (f16*)(smem + 40960);        // [64][64]  swizzled (fc2 -> fc3)
  f16* f2 = (f16*)(smem + 49152);        // [64][32]  plain

  const int tid = threadIdx.x;
  const int lane = tid & 63, wid = tid >> 6;
  const int l15 = lane & 15, lk = lane >> 4, kb = lk * 8;
  const long long base = (long long)blockIdx.x * 64;

  { // positional encoding (sin/cos) + policy layer 1  (fp32 VALU, packed b64 writes)
    int r = lane, d8 = wid;              // row = lane (0..63), dims d8*4 .. d8*4+3
    float4 xv = ((const float4*)x)[base + r];
    f16x4 sv, cv, pv;
    #pragma unroll
    for (int j = 0; j < 4; ++j){
      int d = d8 * 4 + j;
      float4 w = ((const float4*)pe_w)[d];
      float u = fmaf(xv.x, w.x, fmaf(xv.y, w.y, fmaf(xv.z, w.z, fmaf(xv.w, w.w, pe_b[d]))));
      sv[j] = (f16)fsin(u);
      cv[j] = (f16)fcos(u);
      float4 wp = ((const float4*)p1_w)[d];
      float z = 30.0f * fmaf(xv.x, wp.x, fmaf(xv.y, wp.y, fmaf(xv.z, wp.z, fmaf(xv.w, wp.w, p1_b[d]))));
      pv[j] = (f16)fsin(z);
    }
    *(f16x4*)(h0 + r * 72 + d8 * 4)      = sv;
    *(f16x4*)(h0 + r * 72 + 32 + d8 * 4) = cv;
    *(f16x4*)(f1 + r * 40 + d8 * 4)      = pv;
  }
  __syncthreads();   // A

  { // policy layer 2 (swapped): 8 tiles = 2ct x 4rt, one per wave -> f2
    int ct = wid & 1, rt2 = wid >> 1;
    float4 bias = *(const float4*)(bws + FB_P2 + ct * 16 + lk * 4);
    f16x8 wv = *(const f16x8*)(ws + OFF_WP2 + (ct * 16 + l15) * 32 + kb);
    f16x8 a  = *(const f16x8*)(f1 + (rt2 * 16 + l15) * 40 + kb);
    f32x4 acc = {bias.x, bias.y, bias.z, bias.w};
    acc = __builtin_amdgcn_mfma_f32_16x16x32_f16(wv, a, acc, 0, 0, 0);
    int r = rt2 * 16 + l15, n0 = ct * 16 + lk * 4;
    f16x4 o;
    o[0] = (f16)fsin(acc[0]); o[1] = (f16)fsin(acc[1]);
    o[2] = (f16)fsin(acc[2]); o[3] = (f16)fsin(acc[3]);
    *(f16x4*)(f2 + r * 32 + n0) = o;
  }
  // no barrier: f2 only read at gate; s1 below reads h0/writes h1 (disjoint).

  // SIREN s1: [64,64]->[64,128], sin.   ct=wid (1), rt 0..3. af[4][2]=32. (barrier B)
  MM_LAYER(64, h0, 72, IDXP, 1, wid, 0, 4, OFF_W1, FB_B1,
           STORE4(h1, 128, IDXS, fsin(v0), fsin(v1), fsin(v2), fsin(v3)))
  // SIREN s2: [64,128]->[64,256], sin.  ct={w>>1 +4j} (4), rtg=w&1 (2). af[2][4]=32. (barrier C)
  MM_LAYER(128, h1, 128, IDXS, 4, ((wid >> 1) + jj * 4), (wid & 1) * 2, 2, OFF_W2, FB_B2,
           STORE4(h2, 256, IDXS, fsin(v0), fsin(v1), fsin(v2), fsin(v3)))
  // fc1: [64,256]->[64,64], relu.  ct=(w>>2)*2+jj (2), rt=w&3 (1). af[1][8]=32. (barrier D)
  MM_LAYER(256, h2, 256, IDXS, 2, ((wid >> 2) * 2 + jj), (wid & 3), 1, OFF_WF1, FB_F1,
           STORE4(t1, 64, IDXS, fmaxf(v0, 0.f), fmaxf(v1, 0.f), fmaxf(v2, 0.f), fmaxf(v3, 0.f)))
  // fc2: [64,64]->[64,64], relu.   same split, af[1][2]=8.                (barrier E)
  MM_LAYER(64, t1, 64, IDXS, 2, ((wid >> 2) * 2 + jj), (wid & 3), 1, OFF_WF2, FB_F2,
           STORE4(t2, 64, IDXS, fmaxf(v0, 0.f), fmaxf(v1, 0.f), fmaxf(v2, 0.f), fmaxf(v3, 0.f)))
  // fc3 + residual IN PLACE: h2 <- relu(t2@W3 + h2). ct=(w>>2)*8+jj (8), rt=w&3 (1). (barrier F)
  MM_LAYER(64, t2, 64, IDXS, 8, ((wid >> 2) * 8 + jj), (wid & 3), 1, OFF_WF3, FB_F3,
           f16x4 old = *(const f16x4*)(h2 + IDXS(r, n0, 256));
           STORE4(h2, 256, IDXS, fmaxf(v0 + (float)old[0], 0.f), fmaxf(v1 + (float)old[1], 0.f),
                                 fmaxf(v2 + (float)old[2], 0.f), fmaxf(v3 + (float)old[3], 0.f)))

  { // gate + experts fused (A = activations), softmax + routing in-wave
    if (wid < 4){
      int rt4 = wid;                       // rows rt4*16 .. rt4*16+15
      float bias = bws[FB_GE + l15];
      f32x4 acc = {bias, bias, bias, bias};
      #pragma unroll
      for (int ks = 0; ks < 8; ks++){
        f16x8 a = *(const f16x8*)(h2 + IDXS((rt4 * 16 + l15), (ks * 32 + kb), 256));
        f16x8 b = *(const f16x8*)(ws + OFF_WGE + l15 * 288 + ks * 32 + kb);
        acc = __builtin_amdgcn_mfma_f32_16x16x32_f16(a, b, acc, 0, 0, 0);
      }
      { // ks = 8: policy features from f2
        f16x8 a = *(const f16x8*)(f2 + (rt4 * 16 + l15) * 32 + kb);
        f16x8 b = *(const f16x8*)(ws + OFF_WGE + l15 * 288 + 256 + kb);
        acc = __builtin_amdgcn_mfma_f32_16x16x32_f16(a, b, acc, 0, 0, 0);
      }
      // D layout: col = l15 (0..6 logits, 8..14 preds), row = rt4*16 + lk*4 + i.
      #pragma unroll
      for (int i = 0; i < 4; i++){
        float v = acc[i];
        float pred = __shfl_xor(v, 8);          // lane e (<7) gets expert e's pred
        float lg = (l15 < 7) ? v : -1e30f;
        float m = lg;
        m = fmaxf(m, __shfl_xor(m, 1));
        m = fmaxf(m, __shfl_xor(m, 2));
        m = fmaxf(m, __shfl_xor(m, 4));
        float p = __expf(lg - m);               // lane 7: exp(-1e30 - m) = 0
        float c = p * pred;
        float s = p, y = c;
        s += __shfl_xor(s, 1); y += __shfl_xor(y, 1);
        s += __shfl_xor(s, 2); y += __shfl_xor(y, 2);
        s += __shfl_xor(s, 4); y += __shfl_xor(y, 4);
        if (l15 == 0) out[base + rt4 * 16 + lk * 4 + i] = y / s;
      }
    }
  }
}

extern "C" void kernel_launch(void* const* d_in, const int* in_sizes, int n_in,
                              void* d_out, int out_size, void* d_ws, size_t ws_size,
                              hipStream_t stream)
{
  const float* x     = (const float*)d_in[0];
  const float* pe_w  = (const float*)d_in[1];
  const float* pe_b  = (const float*)d_in[2];
  const float* s1_w  = (const float*)d_in[3];
  const float* s1_b  = (const float*)d_in[4];
  const float* s2_w  = (const float*)d_in[5];
  const float* s2_b  = (const float*)d_in[6];
  const float* fc1_w = (const float*)d_in[7];
  const float* fc1_b = (const float*)d_in[8];
  const float* fc2_w = (const float*)d_in[9];
  const float* fc2_b = (const float*)d_in[10];
  const float* fc3_w = (const float*)d_in[11];
  const float* fc3_b = (const float*)d_in[12];
  const float* p1_w  = (const float*)d_in[13];
  const float* p1_b  = (const float*)d_in[14];
  const float* p2_w  = (const float*)d_in[15];
  const float* p2_b  = (const float*)d_in[16];
  const float* gate_w= (const float*)d_in[17];
  const float* gate_b= (const float*)d_in[18];
  const float* exp_w = (const float*)d_in[19];
  const float* exp_b = (const float*)d_in[20];
  f16* ws = (f16*)d_ws;

  convert_w<<<128, 256, 0, stream>>>(s1_w, s1_b, s2_w, s2_b, fc1_w, fc1_b, fc2_w, fc2_b,
                                     fc3_w, fc3_b, gate_w, gate_b, exp_w, exp_b, p2_w, p2_b, ws);
  moe_main<<<524288 / 64, 512, 0, stream>>>(x, pe_w, pe_b, p1_w, p1_b, ws, (float*)d_out);
}

// Round 7
// 253.834 us; speedup vs baseline: 1.8305x; 1.8305x over previous
//
#include <hip/hip_runtime.h>

typedef _Float16 f16;
typedef _Float16 f16x4 __attribute__((ext_vector_type(4)));
typedef _Float16 f16x8 __attribute__((ext_vector_type(8)));
typedef float f32x4 __attribute__((ext_vector_type(4)));

// ---- f16 weight arena layout in d_ws (units: halfs) ----
#define OFF_W1  0            // s1_w *30   [128][64]
#define OFF_W2  8192         // s2_w *30   [256][128]
#define OFF_WF1 40960        // fc1_w      [64][256]
#define OFF_WF2 57344        // fc2_w      [64][64]
#define OFF_WF3 61440        // fc3_w      [256][64]
#define OFF_WGE 77824        // [16][288]: rows 0..6 gate_w, 8..14 exp_w (cols<256), rest 0
#define OFF_WP2 82432        // p2_w *30   [32][32]
#define TOTH    83456
// ---- fp32 bias arena at (float*)(ws + TOTH), units: floats ----
#define FB_B1  0             // 30*s1_b (128)
#define FB_B2  128           // 30*s2_b (256)
#define FB_F1  384           // fc1_b (64)
#define FB_F2  448           // fc2_b (64)
#define FB_F3  512           // fc3_b (256)
#define FB_GE  768           // gate_b(0..6), 0, exp_b(8..14), 0
#define FB_P2  784           // 30*p2_b (32)

// sin(x): v_sin_f32 takes revolutions, 1-periodic -> fract is a valid reduction.
__device__ __forceinline__ float fsin(float x){
  return __builtin_amdgcn_sinf(__builtin_amdgcn_fractf(x * 0.15915494309189535f));
}
__device__ __forceinline__ float fcos(float x){
  return __builtin_amdgcn_sinf(__builtin_amdgcn_fractf(
      fmaf(x, 0.15915494309189535f, 0.25f)));
}

// ---------- weight conversion: fp32 -> f16, OMEGA folded ----------
__global__ void convert_w(const float* __restrict__ s1w, const float* __restrict__ s1b,
                          const float* __restrict__ s2w, const float* __restrict__ s2b,
                          const float* __restrict__ f1w, const float* __restrict__ f1b,
                          const float* __restrict__ f2w, const float* __restrict__ f2b,
                          const float* __restrict__ f3w, const float* __restrict__ f3b,
                          const float* __restrict__ gw,  const float* __restrict__ gb,
                          const float* __restrict__ ew,  const float* __restrict__ eb,
                          const float* __restrict__ p2w, const float* __restrict__ p2b,
                          f16* __restrict__ ws)
{
  int stride = gridDim.x * blockDim.x;
  int tid0 = blockIdx.x * blockDim.x + threadIdx.x;
  for (int i = tid0; i < TOTH; i += stride){
    float v;
    if (i < OFF_W2)       v = 30.0f * s1w[i];
    else if (i < OFF_WF1) v = 30.0f * s2w[i - OFF_W2];
    else if (i < OFF_WF2) v = f1w[i - OFF_WF1];
    else if (i < OFF_WF3) v = f2w[i - OFF_WF2];
    else if (i < OFF_WGE) v = f3w[i - OFF_WF3];
    else if (i < OFF_WP2){
      int j = i - OFF_WGE; int row = j / 288; int col = j - row * 288;
      v = (row < 7) ? gw[row * 288 + col]
        : ((row >= 8 && row < 15 && col < 256) ? ew[(row - 8) * 256 + col] : 0.0f);
    }
    else v = 30.0f * p2w[i - OFF_WP2];
    ws[i] = (f16)v;
  }
  float* bws = (float*)(ws + TOTH);
  for (int i = tid0; i < 816; i += stride){
    float v;
    if (i < 128)      v = 30.0f * s1b[i];
    else if (i < 384) v = 30.0f * s2b[i - 128];
    else if (i < 448) v = f1b[i - 384];
    else if (i < 512) v = f2b[i - 448];
    else if (i < 768) v = f3b[i - 512];
    else if (i < 784){ int j = i - 768;
      v = (j < 7) ? gb[j] : ((j >= 8 && j < 15) ? eb[j - 8] : 0.0f); }
    else v = 30.0f * p2b[i - 784];
    bws[i] = v;
  }
}

#define STORE4(P_, S_, E0_, E1_, E2_, E3_)                                           \
  { f16x4 o; o[0] = (f16)(E0_); o[1] = (f16)(E1_); o[2] = (f16)(E2_); o[3] = (f16)(E3_); \
    *(f16x4*)((P_) + r * (S_) + n0) = o; }

// Layer pass, ILP-front-loaded: (1) ALL global weight+bias loads issued first
// (longest latency), (2) all LDS activation loads, (3) MFMA block with NRT
// independent accumulator chains, (4) epilogue. Bias folded into MFMA C-init.
// R6 lesson: serial per-jj load->mfma chains stall 74% of cycles; R4 lesson:
// NRT=4 independent chains is what made 260us. Epilogue sees r, n0, v0..v3.
#define MM_LAYER(K_, ACT_, SA_, NCT_, CTEXPR_, RT0_, NRT_, WOFF_, BOFF_, ...)        \
  {                                                                                  \
    int cts[NCT_];                                                                   \
    _Pragma("unroll")                                                                \
    for (int jj = 0; jj < (NCT_); ++jj) cts[jj] = (CTEXPR_);                         \
    f16x8 wv[NCT_][(K_) / 32];                                                       \
    float4 bias[NCT_];                                                               \
    _Pragma("unroll")                                                                \
    for (int jj = 0; jj < (NCT_); ++jj){                                             \
      _Pragma("unroll")                                                              \
      for (int ks = 0; ks < (K_) / 32; ++ks)                                         \
        wv[jj][ks] = *(const f16x8*)(ws + (WOFF_) + (cts[jj] * 16 + l15) * (K_) + ks * 32 + kb); \
      bias[jj] = *(const float4*)(bws + (BOFF_) + cts[jj] * 16 + lk * 4);            \
    }                                                                                \
    f16x8 af[NRT_][(K_) / 32];                                                       \
    _Pragma("unroll")                                                                \
    for (int rr = 0; rr < (NRT_); ++rr)                                              \
      _Pragma("unroll")                                                              \
      for (int ks = 0; ks < (K_) / 32; ++ks)                                         \
        af[rr][ks] = *(const f16x8*)((ACT_) + (((RT0_) + rr) * 16 + l15) * (SA_) + ks * 32 + kb); \
    _Pragma("unroll")                                                                \
    for (int jj = 0; jj < (NCT_); ++jj){                                             \
      f32x4 acc[NRT_];                                                               \
      _Pragma("unroll")                                                              \
      for (int rr = 0; rr < (NRT_); ++rr)                                            \
        acc[rr] = (f32x4){bias[jj].x, bias[jj].y, bias[jj].z, bias[jj].w};           \
      _Pragma("unroll")                                                              \
      for (int ks = 0; ks < (K_) / 32; ++ks)                                         \
        _Pragma("unroll")                                                            \
        for (int rr = 0; rr < (NRT_); ++rr)                                          \
          acc[rr] = __builtin_amdgcn_mfma_f32_16x16x32_f16(wv[jj][ks], af[rr][ks], acc[rr], 0, 0, 0); \
      const int n0 = cts[jj] * 16 + lk * 4;                                          \
      _Pragma("unroll")                                                              \
      for (int rr = 0; rr < (NRT_); ++rr){                                           \
        const int r = ((RT0_) + rr) * 16 + l15;                                      \
        float v0 = acc[rr][0], v1 = acc[rr][1], v2 = acc[rr][2], v3 = acc[rr][3];    \
        __VA_ARGS__;                                                                 \
      }                                                                              \
    }                                                                                \
  }                                                                                  \
  __syncthreads();

__global__ __launch_bounds__(512, 4) void moe_main(
    const float* __restrict__ x,
    const float* __restrict__ pe_w, const float* __restrict__ pe_b,
    const float* __restrict__ p1_w, const float* __restrict__ p1_b,
    const f16* __restrict__ ws, float* __restrict__ out)
{
  const float* bws = (const float*)(ws + TOTH);
  __shared__ __align__(16) unsigned char smem[65536];
  f16* h0 = (f16*)smem;                  // [64][72]  PE out; overlay t1 [64][72]
  f16* t1 = (f16*)smem;
  f16* h1 = (f16*)(smem + 9216);         // [64][136] s1 out; overlay t2 [64][136]
  f16* t2 = (f16*)(smem + 9216);
  f16* h2 = (f16*)(smem + 26624);        // [64][264] s2 out; fc3 in-place; f1 overlay
  f16* f1 = (f16*)(smem + 26624);        // [64][40]  policy layer-1 (dead before s2)
  f16* f2 = (f16*)(smem + 60416);        // [64][40]  policy layer-2 out

  const int tid = threadIdx.x;
  const int lane = tid & 63, wid = tid >> 6;
  const int l15 = lane & 15, lk = lane >> 4, kb = lk * 8;
  const long long base = (long long)blockIdx.x * 64;

  { // positional encoding (sin/cos) + policy layer 1  (fp32 VALU, packed b64 writes)
    int r = lane, d8 = wid;              // row = lane (0..63), dims d8*4 .. d8*4+3
    float4 xv = ((const float4*)x)[base + r];
    f16x4 sv, cv, pv;
    #pragma unroll
    for (int j = 0; j < 4; ++j){
      int d = d8 * 4 + j;
      float4 w = ((const float4*)pe_w)[d];
      float u = fmaf(xv.x, w.x, fmaf(xv.y, w.y, fmaf(xv.z, w.z, fmaf(xv.w, w.w, pe_b[d]))));
      sv[j] = (f16)fsin(u);
      cv[j] = (f16)fcos(u);
      float4 wp = ((const float4*)p1_w)[d];
      float z = 30.0f * fmaf(xv.x, wp.x, fmaf(xv.y, wp.y, fmaf(xv.z, wp.z, fmaf(xv.w, wp.w, p1_b[d]))));
      pv[j] = (f16)fsin(z);
    }
    *(f16x4*)(h0 + r * 72 + d8 * 4)      = sv;
    *(f16x4*)(h0 + r * 72 + 32 + d8 * 4) = cv;
    *(f16x4*)(f1 + r * 40 + d8 * 4)      = pv;
  }
  __syncthreads();   // A

  { // policy layer 2 (swapped): 8 tiles = 2ct x 4rt, one per wave -> f2
    int ct = wid & 1, rt2 = wid >> 1;
    float4 bias = *(const float4*)(bws + FB_P2 + ct * 16 + lk * 4);
    f16x8 wv = *(const f16x8*)(ws + OFF_WP2 + (ct * 16 + l15) * 32 + kb);
    f16x8 a  = *(const f16x8*)(f1 + (rt2 * 16 + l15) * 40 + kb);
    f32x4 acc = {bias.x, bias.y, bias.z, bias.w};
    acc = __builtin_amdgcn_mfma_f32_16x16x32_f16(wv, a, acc, 0, 0, 0);
    int r = rt2 * 16 + l15, n0 = ct * 16 + lk * 4;
    f16x4 o;
    o[0] = (f16)fsin(acc[0]); o[1] = (f16)fsin(acc[1]);
    o[2] = (f16)fsin(acc[2]); o[3] = (f16)fsin(acc[3]);
    *(f16x4*)(f2 + r * 40 + n0) = o;
  }
  // no barrier: f2 only read at gate; s1 below reads h0 / writes h1 (disjoint).

  // SIREN s1: [64,64] -> [64,128], sin      ct = wid, rt 0..3            (barrier B)
  MM_LAYER(64, h0, 72, 1, wid, 0, 4, OFF_W1, FB_B1,
           STORE4(h1, 136, fsin(v0), fsin(v1), fsin(v2), fsin(v3)))
  // SIREN s2: [64,128] -> [64,256], sin     ct = {wid, wid+8}, rt 0..3   (barrier C)
  MM_LAYER(128, h1, 136, 2, (wid + jj * 8), 0, 4, OFF_W2, FB_B2,
           STORE4(h2, 264, fsin(v0), fsin(v1), fsin(v2), fsin(v3)))
  // fc1: [64,256] -> [64,64], relu          ct = wid&3, rt-pair = wid>>2 (barrier D)
  MM_LAYER(256, h2, 264, 1, (wid & 3), (wid >> 2) * 2, 2, OFF_WF1, FB_F1,
           STORE4(t1, 72, fmaxf(v0, 0.f), fmaxf(v1, 0.f), fmaxf(v2, 0.f), fmaxf(v3, 0.f)))
  // fc2: [64,64] -> [64,64], relu                                        (barrier E)
  MM_LAYER(64, t1, 72, 1, (wid & 3), (wid >> 2) * 2, 2, OFF_WF2, FB_F2,
           STORE4(t2, 136, fmaxf(v0, 0.f), fmaxf(v1, 0.f), fmaxf(v2, 0.f), fmaxf(v3, 0.f)))
  // fc3 + residual IN PLACE: h2 <- relu(t2@W3 + h2)                      (barrier F)
  MM_LAYER(64, t2, 136, 2, (wid + jj * 8), 0, 4, OFF_WF3, FB_F3,
           f16x4 old = *(const f16x4*)(h2 + r * 264 + n0);
           STORE4(h2, 264, fmaxf(v0 + (float)old[0], 0.f), fmaxf(v1 + (float)old[1], 0.f),
                           fmaxf(v2 + (float)old[2], 0.f), fmaxf(v3 + (float)old[3], 0.f)))

  { // gate + experts fused (A = activations), softmax + routing in-wave
    if (wid < 4){
      int rt4 = wid;                       // rows rt4*16 .. rt4*16+15
      float bias = bws[FB_GE + l15];
      // front-load all B-frags (global) then A-frags (LDS)
      f16x8 bfr[9], afr[9];
      #pragma unroll
      for (int ks = 0; ks < 9; ks++)
        bfr[ks] = *(const f16x8*)(ws + OFF_WGE + l15 * 288 + ks * 32 + kb);
      #pragma unroll
      for (int ks = 0; ks < 8; ks++)
        afr[ks] = *(const f16x8*)(h2 + (rt4 * 16 + l15) * 264 + ks * 32 + kb);
      afr[8] = *(const f16x8*)(f2 + (rt4 * 16 + l15) * 40 + kb);
      f32x4 acc = {bias, bias, bias, bias};
      #pragma unroll
      for (int ks = 0; ks < 9; ks++)
        acc = __builtin_amdgcn_mfma_f32_16x16x32_f16(afr[ks], bfr[ks], acc, 0, 0, 0);
      // D layout: col = l15 (0..6 logits, 8..14 preds), row = rt4*16 + lk*4 + i.
      #pragma unroll
      for (int i = 0; i < 4; i++){
        float v = acc[i];
        float pred = __shfl_xor(v, 8);          // lane e (<7) gets expert e's pred
        float lg = (l15 < 7) ? v : -1e30f;
        float m = lg;
        m = fmaxf(m, __shfl_xor(m, 1));
        m = fmaxf(m, __shfl_xor(m, 2));
        m = fmaxf(m, __shfl_xor(m, 4));
        float p = __expf(lg - m);               // lane 7: exp(-1e30 - m) = 0
        float c = p * pred;
        float s = p, y = c;
        s += __shfl_xor(s, 1); y += __shfl_xor(y, 1);
        s += __shfl_xor(s, 2); y += __shfl_xor(y, 2);
        s += __shfl_xor(s, 4); y += __shfl_xor(y, 4);
        if (l15 == 0) out[base + rt4 * 16 + lk * 4 + i] = y / s;
      }
    }
  }
}

extern "C" void kernel_launch(void* const* d_in, const int* in_sizes, int n_in,
                              void* d_out, int out_size, void* d_ws, size_t ws_size,
                              hipStream_t stream)
{
  const float* x     = (const float*)d_in[0];
  const float* pe_w  = (const float*)d_in[1];
  const float* pe_b  = (const float*)d_in[2];
  const float* s1_w  = (const float*)d_in[3];
  const float* s1_b  = (const float*)d_in[4];
  const float* s2_w  = (const float*)d_in[5];
  const float* s2_b  = (const float*)d_in[6];
  const float* fc1_w = (const float*)d_in[7];
  const float* fc1_b = (const float*)d_in[8];
  const float* fc2_w = (const float*)d_in[9];
  const float* fc2_b = (const float*)d_in[10];
  const float* fc3_w = (const float*)d_in[11];
  const float* fc3_b = (const float*)d_in[12];
  const float* p1_w  = (const float*)d_in[13];
  const float* p1_b  = (const float*)d_in[14];
  const float* p2_w  = (const float*)d_in[15];
  const float* p2_b  = (const float*)d_in[16];
  const float* gate_w= (const float*)d_in[17];
  const float* gate_b= (const float*)d_in[18];
  const float* exp_w = (const float*)d_in[19];
  const float* exp_b = (const float*)d_in[20];
  f16* ws = (f16*)d_ws;

  convert_w<<<128, 256, 0, stream>>>(s1_w, s1_b, s2_w, s2_b, fc1_w, fc1_b, fc2_w, fc2_b,
                                     fc3_w, fc3_b, gate_w, gate_b, exp_w, exp_b, p2_w, p2_b, ws);
  moe_main<<<524288 / 64, 512, 0, stream>>>(x, pe_w, pe_b, p1_w, p1_b, ws, (float*)d_out);
}

// Round 8
// 245.228 us; speedup vs baseline: 1.8947x; 1.0351x over previous
//
#include <hip/hip_runtime.h>

typedef _Float16 f16;
typedef _Float16 f16x4 __attribute__((ext_vector_type(4)));
typedef _Float16 f16x8 __attribute__((ext_vector_type(8)));
typedef float f32x4 __attribute__((ext_vector_type(4)));

// ---- f16 weight arena in d_ws (units: halfs) ----
// [0, 77824): LDS image, kappa-permuted + XOR-swizzled, row-major:
#define L_W1   0             // s1_w *30   [128][64]
#define L_W2   8192          // s2_w *30   [256][128]
#define L_WF1  40960         // fc1_w      [64][256]
#define L_WF2  57344         // fc2_w      [64][64]
#define L_WF3  61440         // fc3_w      [256][64]
#define LIMG   77824         // LDS image halfs (155648 B)
#define OFF_WGE 77824        // [16][288] kappa-permuted (no swz): rows 0-6 gate, 8-14 experts
#define OFF_WP2 82432        // p2_w *30  [32][32] kappa-permuted (no swz)
#define TOTH    83456
// ---- fp32 bias arena at (float*)(ws + TOTH) ----
#define FB_B1  0
#define FB_B2  128
#define FB_F1  384
#define FB_F2  448
#define FB_F3  512
#define FB_GE  768           // gate_b(0..6), 0, exp_b(8..14), 0
#define FB_P2  784

__device__ __forceinline__ float fsin(float x){
  return __builtin_amdgcn_sinf(__builtin_amdgcn_fractf(x * 0.15915494309189535f));
}
__device__ __forceinline__ float fcos(float x){
  return __builtin_amdgcn_sinf(__builtin_amdgcn_fractf(
      fmaf(x, 0.15915494309189535f, 0.25f)));
}

// kappa-permutation: B-operand slot kappa (within a 32-K chunk) <- logical column.
// Derivation: held quad (ct,lk) = logical cols ct*16+4lk..+3; B-frag half h of
// slot kappa=8lk+h must be logical 16*(h>>2)+4lk+(h&3).
__device__ __forceinline__ int permk(int k){
  return 16 * ((k & 7) >> 2) + ((k >> 3) & 3) * 4 + (k & 3);
}

// ---------- weight conversion: fp32 -> f16, OMEGA folded, perm+swizzle ----------
__global__ void convert_w(const float* __restrict__ s1w, const float* __restrict__ s1b,
                          const float* __restrict__ s2w, const float* __restrict__ s2b,
                          const float* __restrict__ f1w, const float* __restrict__ f1b,
                          const float* __restrict__ f2w, const float* __restrict__ f2b,
                          const float* __restrict__ f3w, const float* __restrict__ f3b,
                          const float* __restrict__ gw,  const float* __restrict__ gb,
                          const float* __restrict__ ew,  const float* __restrict__ eb,
                          const float* __restrict__ p2w, const float* __restrict__ p2b,
                          f16* __restrict__ ws)
{
  int stride = gridDim.x * blockDim.x;
  int t0 = blockIdx.x * blockDim.x + threadIdx.x;
  for (int i = t0; i < TOTH; i += stride){
    float v;
    if (i < L_W2){                         // W1 [128][64], swz, *30
      int r = i >> 6, s = i & 63, k = s ^ ((r & 7) << 3);
      v = 30.f * s1w[(r << 6) + (k & 32) + permk(k & 31)];
    } else if (i < L_WF1){                 // W2 [256][128], swz, *30
      int j = i - L_W2, r = j >> 7, s = j & 127, k = s ^ ((r & 7) << 3);
      v = 30.f * s2w[(r << 7) + (k & 96) + permk(k & 31)];
    } else if (i < L_WF2){                 // WF1 [64][256], swz
      int j = i - L_WF1, r = j >> 8, s = j & 255, k = s ^ ((r & 7) << 3);
      v = f1w[(r << 8) + (k & 224) + permk(k & 31)];
    } else if (i < L_WF3){                 // WF2 [64][64], swz
      int j = i - L_WF2, r = j >> 6, s = j & 63, k = s ^ ((r & 7) << 3);
      v = f2w[(r << 6) + (k & 32) + permk(k & 31)];
    } else if (i < OFF_WGE){               // WF3 [256][64], swz
      int j = i - L_WF3, r = j >> 6, s = j & 63, k = s ^ ((r & 7) << 3);
      v = f3w[(r << 6) + (k & 32) + permk(k & 31)];
    } else if (i < OFF_WP2){               // WGE [16][288], perm only
      int j = i - OFF_WGE, r = j / 288, k = j - r * 288;
      int p = (k & ~31) + permk(k & 31);
      v = (r < 7) ? gw[r * 288 + p]
        : ((r >= 8 && r < 15 && p < 256) ? ew[(r - 8) * 256 + p] : 0.f);
    } else {                               // WP2 [32][32], perm only, *30
      int j = i - OFF_WP2, r = j >> 5, k = j & 31;
      v = 30.f * p2w[(r << 5) + permk(k)];
    }
    ws[i] = (f16)v;
  }
  float* bws = (float*)(ws + TOTH);
  for (int i = t0; i < 816; i += stride){
    float v;
    if (i < 128)      v = 30.0f * s1b[i];
    else if (i < 384) v = 30.0f * s2b[i - 128];
    else if (i < 448) v = f1b[i - 384];
    else if (i < 512) v = f2b[i - 448];
    else if (i < 768) v = f3b[i - 512];
    else if (i < 784){ int j = i - 768;
      v = (j < 7) ? gb[j] : ((j >= 8 && j < 15) ? eb[j - 8] : 0.0f); }
    else v = 30.0f * p2b[i - 784];
    bws[i] = v;
  }
}

__device__ __forceinline__ f16x4 sin4(f32x4 a){
  f16x4 o; o[0]=(f16)fsin(a[0]); o[1]=(f16)fsin(a[1]);
  o[2]=(f16)fsin(a[2]); o[3]=(f16)fsin(a[3]); return o;
}
__device__ __forceinline__ f16x4 relu4(f32x4 a){
  f16x4 o; o[0]=(f16)fmaxf(a[0],0.f); o[1]=(f16)fmaxf(a[1],0.f);
  o[2]=(f16)fmaxf(a[2],0.f); o[3]=(f16)fmaxf(a[3],0.f); return o;
}
__device__ __forceinline__ f16x4 resrelu4(f32x4 a, f16x4 old){
  f16x4 o;
  o[0]=(f16)fmaxf(a[0]+(float)old[0],0.f); o[1]=(f16)fmaxf(a[1]+(float)old[1],0.f);
  o[2]=(f16)fmaxf(a[2]+(float)old[2],0.f); o[3]=(f16)fmaxf(a[3]+(float)old[3],0.f);
  return o;
}

// In-register layer: NT output tiles, NKS K-chunks. Weights from swizzled LDS,
// activations from held quads (INq), outputs to held quads via OUTSTMT(ct, acc).
#define LAYER_LDS(NT_, NKS_, LOFF_, BOFF_, INq_, OUTSTMT_)                        \
  _Pragma("unroll")                                                               \
  for (int ct = 0; ct < (NT_); ++ct){                                             \
    float4 b4 = *(const float4*)(bws + (BOFF_) + ct * 16 + lk * 4);               \
    f32x4 acc = {b4.x, b4.y, b4.z, b4.w};                                         \
    _Pragma("unroll")                                                             \
    for (int ks = 0; ks < (NKS_); ++ks){                                          \
      f16x8 wv = *(const f16x8*)(wlds + (LOFF_) + (ct * 16 + l15) * ((NKS_) * 32) \
                                  + ((32 * ks + 8 * lk) ^ swzh));                 \
      f16x8 bf = __builtin_shufflevector((INq_)[2 * ks], (INq_)[2 * ks + 1],      \
                                         0, 1, 2, 3, 4, 5, 6, 7);                 \
      acc = __builtin_amdgcn_mfma_f32_16x16x32_f16(wv, bf, acc, 0, 0, 0);         \
    }                                                                             \
    OUTSTMT_;                                                                     \
  }

__global__ __launch_bounds__(1024, 4) void moe_main(
    const float* __restrict__ x,
    const float* __restrict__ pe_w, const float* __restrict__ pe_b,
    const float* __restrict__ p1_w, const float* __restrict__ p1_b,
    const f16* __restrict__ ws, float* __restrict__ out)
{
  const float* bws = (const float*)(ws + TOTH);
  __shared__ __align__(16) f16 wlds[LIMG];   // 155648 B -> 1 block/CU

  const int tid = threadIdx.x;
  const int lane = tid & 63, wid = tid >> 6;
  const int l15 = lane & 15, lk = lane >> 4;
  const int swzh = (l15 & 7) << 3;           // row = ct*16+l15 -> row&7 = l15&7
  const long long grow = (long long)blockIdx.x * 256 + wid * 16 + l15;

  // ---- stage weights L2 -> LDS (linear, conflict-free) ----
  for (int i = tid * 8; i < LIMG; i += 8192)
    *(float4*)(wlds + i) = *(const float4*)(ws + i);

  // ---- PE + policy-1 (registers only, overlaps staging) ----
  float4 xv = ((const float4*)x)[grow];
  f16x4 h0q[4], f1q[2];
  {
    const float4* pe4 = (const float4*)pe_w;
    const float4* p14 = (const float4*)p1_w;
    #pragma unroll
    for (int c = 0; c < 2; ++c)
      #pragma unroll
      for (int i = 0; i < 4; ++i){
        int d = c * 16 + lk * 4 + i;
        float4 w = pe4[d];
        float u = fmaf(xv.x,w.x,fmaf(xv.y,w.y,fmaf(xv.z,w.z,fmaf(xv.w,w.w,pe_b[d]))));
        h0q[c][i]     = (f16)fsin(u);
        h0q[2 + c][i] = (f16)fcos(u);
        float4 wp = p14[d];
        float z = 30.f*fmaf(xv.x,wp.x,fmaf(xv.y,wp.y,fmaf(xv.z,wp.z,fmaf(xv.w,wp.w,p1_b[d]))));
        f1q[c][i] = (f16)fsin(z);
      }
  }

  // ---- policy-2 (weights from L2, kappa-permuted) ----
  f16x4 f2q[2];
  {
    f16x8 bfp = __builtin_shufflevector(f1q[0], f1q[1], 0,1,2,3,4,5,6,7);
    #pragma unroll
    for (int ct = 0; ct < 2; ++ct){
      float4 b4 = *(const float4*)(bws + FB_P2 + ct * 16 + lk * 4);
      f32x4 acc = {b4.x, b4.y, b4.z, b4.w};
      f16x8 wv = *(const f16x8*)(ws + OFF_WP2 + (ct * 16 + l15) * 32 + 8 * lk);
      acc = __builtin_amdgcn_mfma_f32_16x16x32_f16(wv, bfp, acc, 0, 0, 0);
      f2q[ct] = sin4(acc);
    }
  }

  __syncthreads();   // the ONLY barrier: weights staged

  // ---- SIREN + bottleneck chain, all in registers ----
  f16x4 h1q[8];
  LAYER_LDS(8, 2, L_W1, FB_B1, h0q, h1q[ct] = sin4(acc))
  f16x4 h2s[16];
  LAYER_LDS(16, 4, L_W2, FB_B2, h1q, h2s[ct] = sin4(acc))
  f16x4 t1q[4];
  LAYER_LDS(4, 8, L_WF1, FB_F1, h2s, t1q[ct] = relu4(acc))
  f16x4 t2q[4];
  LAYER_LDS(4, 2, L_WF2, FB_F2, t1q, t2q[ct] = relu4(acc))
  // fc3 + residual in place: h2s <- relu(t2q@W3 + h2s)  (becomes gate input)
  LAYER_LDS(16, 2, L_WF3, FB_F3, t2q, h2s[ct] = resrelu4(acc, h2s[ct]))

  // ---- gate + experts (swapped) + in-wave softmax/routing ----
  {
    float4 gb = ((const float4*)(bws + FB_GE))[lk];
    f32x4 acc = {gb.x, gb.y, gb.z, gb.w};
    #pragma unroll
    for (int ks = 0; ks < 8; ++ks){
      f16x8 wv = *(const f16x8*)(ws + OFF_WGE + l15 * 288 + 32 * ks + 8 * lk);
      f16x8 bf = __builtin_shufflevector(h2s[2*ks], h2s[2*ks+1], 0,1,2,3,4,5,6,7);
      acc = __builtin_amdgcn_mfma_f32_16x16x32_f16(wv, bf, acc, 0, 0, 0);
    }
    {
      f16x8 wv = *(const f16x8*)(ws + OFF_WGE + l15 * 288 + 256 + 8 * lk);
      f16x8 bf = __builtin_shufflevector(f2q[0], f2q[1], 0,1,2,3,4,5,6,7);
      acc = __builtin_amdgcn_mfma_f32_16x16x32_f16(wv, bf, acc, 0, 0, 0);
    }
    // lane (l15,lk) holds gate rows m=4lk+i for batch row l15:
    // lk=0,1 -> logits 0..7 (7=pad), lk=2,3 -> preds 8..15.
    float pred[4], lg[4];
    #pragma unroll
    for (int i = 0; i < 4; ++i) pred[i] = __shfl_xor(acc[i], 32);
    #pragma unroll
    for (int i = 0; i < 4; ++i) lg[i] = acc[i];
    if (lk == 1) lg[3] = -1e30f;               // gate row 7 = padding
    float mx = fmaxf(fmaxf(lg[0], lg[1]), fmaxf(lg[2], lg[3]));
    mx = fmaxf(mx, __shfl_xor(mx, 16));
    float s = 0.f, y = 0.f;
    #pragma unroll
    for (int i = 0; i < 4; ++i){ float p = __expf(lg[i] - mx); s += p; y += p * pred[i]; }
    s += __shfl_xor(s, 16); y += __shfl_xor(y, 16);
    if (lk == 0) out[grow] = y / s;
  }
}

extern "C" void kernel_launch(void* const* d_in, const int* in_sizes, int n_in,
                              void* d_out, int out_size, void* d_ws, size_t ws_size,
                              hipStream_t stream)
{
  const float* x     = (const float*)d_in[0];
  const float* pe_w  = (const float*)d_in[1];
  const float* pe_b  = (const float*)d_in[2];
  const float* s1_w  = (const float*)d_in[3];
  const float* s1_b  = (const float*)d_in[4];
  const float* s2_w  = (const float*)d_in[5];
  const float* s2_b  = (const float*)d_in[6];
  const float* fc1_w = (const float*)d_in[7];
  const float* fc1_b = (const float*)d_in[8];
  const float* fc2_w = (const float*)d_in[9];
  const float* fc2_b = (const float*)d_in[10];
  const float* fc3_w = (const float*)d_in[11];
  const float* fc3_b = (const float*)d_in[12];
  const float* p1_w  = (const float*)d_in[13];
  const float* p1_b  = (const float*)d_in[14];
  const float* p2_w  = (const float*)d_in[15];
  const float* p2_b  = (const float*)d_in[16];
  const float* gate_w= (const float*)d_in[17];
  const float* gate_b= (const float*)d_in[18];
  const float* exp_w = (const float*)d_in[19];
  const float* exp_b = (const float*)d_in[20];
  f16* ws = (f16*)d_ws;

  convert_w<<<128, 256, 0, stream>>>(s1_w, s1_b, s2_w, s2_b, fc1_w, fc1_b, fc2_w, fc2_b,
                                     fc3_w, fc3_b, gate_w, gate_b, exp_w, exp_b, p2_w, p2_b, ws);
  moe_main<<<524288 / 256, 1024, 0, stream>>>(x, pe_w, pe_b, p1_w, p1_b, ws, (float*)d_out);
}

// Round 9
// 183.657 us; speedup vs baseline: 2.5299x; 1.3352x over previous
//
#include <hip/hip_runtime.h>

typedef _Float16 f16;
typedef _Float16 f16x4 __attribute__((ext_vector_type(4)));
typedef _Float16 f16x8 __attribute__((ext_vector_type(8)));
typedef float f32x4 __attribute__((ext_vector_type(4)));

// ---- f16 weight arena in d_ws (units: halfs) ----
// [0, 77824): LDS image, kappa-permuted + XOR-swizzled, row-major:
#define L_W1   0             // s1_w *30/2pi   [128][64]
#define L_W2   8192          // s2_w *30/2pi   [256][128]
#define L_WF1  40960         // fc1_w          [64][256]
#define L_WF2  57344         // fc2_w          [64][64]
#define L_WF3  61440         // fc3_w          [256][64]
#define LIMG   77824         // LDS image halfs (155648 B)
#define OFF_WGE 77824        // [16][288] kappa-permuted (no swz): rows 0-6 gate, 8-14 experts
#define OFF_WP2 82432        // p2_w *30/2pi  [32][32] kappa-permuted (no swz)
#define TOTH    83456
// ---- fp32 bias arena at (float*)(ws + TOTH) ----
#define FB_B1  0
#define FB_B2  128
#define FB_F1  384
#define FB_F2  448
#define FB_F3  512
#define FB_GE  768           // gate_b(0..6), 0, exp_b(8..14), 0
#define FB_P2  784

#define SIREN_SCL 4.77464829275686f   // 30/(2*pi): folded so sin needs only fract+v_sin

__device__ __forceinline__ float fsin(float x){
  return __builtin_amdgcn_sinf(__builtin_amdgcn_fractf(x * 0.15915494309189535f));
}
__device__ __forceinline__ float fcos(float x){
  return __builtin_amdgcn_sinf(__builtin_amdgcn_fractf(
      fmaf(x, 0.15915494309189535f, 0.25f)));
}
// input already in revolutions (SIREN layers with folded 30/2pi scale)
__device__ __forceinline__ float sin_pre(float v){
  return __builtin_amdgcn_sinf(__builtin_amdgcn_fractf(v));
}

// kappa-permutation: B-operand slot kappa (within a 32-K chunk) <- logical column.
__device__ __forceinline__ int permk(int k){
  return 16 * ((k & 7) >> 2) + ((k >> 3) & 3) * 4 + (k & 3);
}

// ---------- weight conversion: fp32 -> f16, scales folded, perm+swizzle ----------
__global__ void convert_w(const float* __restrict__ s1w, const float* __restrict__ s1b,
                          const float* __restrict__ s2w, const float* __restrict__ s2b,
                          const float* __restrict__ f1w, const float* __restrict__ f1b,
                          const float* __restrict__ f2w, const float* __restrict__ f2b,
                          const float* __restrict__ f3w, const float* __restrict__ f3b,
                          const float* __restrict__ gw,  const float* __restrict__ gb,
                          const float* __restrict__ ew,  const float* __restrict__ eb,
                          const float* __restrict__ p2w, const float* __restrict__ p2b,
                          f16* __restrict__ ws)
{
  int stride = gridDim.x * blockDim.x;
  int t0 = blockIdx.x * blockDim.x + threadIdx.x;
  for (int i = t0; i < TOTH; i += stride){
    float v;
    if (i < L_W2){                         // W1 [128][64], swz, *30/2pi
      int r = i >> 6, s = i & 63, k = s ^ ((r & 7) << 3);
      v = SIREN_SCL * s1w[(r << 6) + (k & 32) + permk(k & 31)];
    } else if (i < L_WF1){                 // W2 [256][128], swz, *30/2pi
      int j = i - L_W2, r = j >> 7, s = j & 127, k = s ^ ((r & 7) << 3);
      v = SIREN_SCL * s2w[(r << 7) + (k & 96) + permk(k & 31)];
    } else if (i < L_WF2){                 // WF1 [64][256], swz
      int j = i - L_WF1, r = j >> 8, s = j & 255, k = s ^ ((r & 7) << 3);
      v = f1w[(r << 8) + (k & 224) + permk(k & 31)];
    } else if (i < L_WF3){                 // WF2 [64][64], swz
      int j = i - L_WF2, r = j >> 6, s = j & 63, k = s ^ ((r & 7) << 3);
      v = f2w[(r << 6) + (k & 32) + permk(k & 31)];
    } else if (i < OFF_WGE){               // WF3 [256][64], swz
      int j = i - L_WF3, r = j >> 6, s = j & 63, k = s ^ ((r & 7) << 3);
      v = f3w[(r << 6) + (k & 32) + permk(k & 31)];
    } else if (i < OFF_WP2){               // WGE [16][288], perm only
      int j = i - OFF_WGE, r = j / 288, k = j - r * 288;
      int p = (k & ~31) + permk(k & 31);
      v = (r < 7) ? gw[r * 288 + p]
        : ((r >= 8 && r < 15 && p < 256) ? ew[(r - 8) * 256 + p] : 0.f);
    } else {                               // WP2 [32][32], perm only, *30/2pi
      int j = i - OFF_WP2, r = j >> 5, k = j & 31;
      v = SIREN_SCL * p2w[(r << 5) + permk(k)];
    }
    ws[i] = (f16)v;
  }
  float* bws = (float*)(ws + TOTH);
  for (int i = t0; i < 816; i += stride){
    float v;
    if (i < 128)      v = SIREN_SCL * s1b[i];
    else if (i < 384) v = SIREN_SCL * s2b[i - 128];
    else if (i < 448) v = f1b[i - 384];
    else if (i < 512) v = f2b[i - 448];
    else if (i < 768) v = f3b[i - 512];
    else if (i < 784){ int j = i - 768;
      v = (j < 7) ? gb[j] : ((j >= 8 && j < 15) ? eb[j - 8] : 0.0f); }
    else v = SIREN_SCL * p2b[i - 784];
    bws[i] = v;
  }
}

__device__ __forceinline__ f16x4 sin4p(f32x4 a){   // pre-scaled (revolutions)
  f16x4 o; o[0]=(f16)sin_pre(a[0]); o[1]=(f16)sin_pre(a[1]);
  o[2]=(f16)sin_pre(a[2]); o[3]=(f16)sin_pre(a[3]); return o;
}
__device__ __forceinline__ f16x4 relu4(f32x4 a){
  f16x4 o; o[0]=(f16)fmaxf(a[0],0.f); o[1]=(f16)fmaxf(a[1],0.f);
  o[2]=(f16)fmaxf(a[2],0.f); o[3]=(f16)fmaxf(a[3],0.f); return o;
}
__device__ __forceinline__ f16x4 resrelu4(f32x4 a, f16x4 old){
  f16x4 o;
  o[0]=(f16)fmaxf(a[0]+(float)old[0],0.f); o[1]=(f16)fmaxf(a[1]+(float)old[1],0.f);
  o[2]=(f16)fmaxf(a[2]+(float)old[2],0.f); o[3]=(f16)fmaxf(a[3]+(float)old[3],0.f);
  return o;
}

// In-register layer: NT output tiles, NKS K-chunks. Weights from swizzled LDS,
// activations from held quads (INq), outputs via OUTSTMT(ct, acc).
#define LAYER_LDS(NT_, NKS_, LOFF_, BOFF_, INq_, OUTSTMT_)                        \
  _Pragma("unroll")                                                               \
  for (int ct = 0; ct < (NT_); ++ct){                                             \
    float4 b4 = *(const float4*)(bws + (BOFF_) + ct * 16 + lk * 4);               \
    f32x4 acc = {b4.x, b4.y, b4.z, b4.w};                                         \
    _Pragma("unroll")                                                             \
    for (int ks = 0; ks < (NKS_); ++ks){                                          \
      f16x8 wv = *(const f16x8*)(wlds + (LOFF_) + (ct * 16 + l15) * ((NKS_) * 32) \
                                  + ((32 * ks + 8 * lk) ^ swzh));                 \
      f16x8 bf = __builtin_shufflevector((INq_)[2 * ks], (INq_)[2 * ks + 1],      \
                                         0, 1, 2, 3, 4, 5, 6, 7);                 \
      acc = __builtin_amdgcn_mfma_f32_16x16x32_f16(wv, bf, acc, 0, 0, 0);         \
    }                                                                             \
    OUTSTMT_;                                                                     \
  }

__global__ __launch_bounds__(512, 2) void moe_main(
    const float* __restrict__ x,
    const float* __restrict__ pe_w, const float* __restrict__ pe_b,
    const float* __restrict__ p1_w, const float* __restrict__ p1_b,
    const f16* __restrict__ ws, float* __restrict__ out)
{
  const float* bws = (const float*)(ws + TOTH);
  __shared__ __align__(16) f16 wlds[LIMG];   // 155648 B -> 1 block/CU, 8 waves

  const int tid = threadIdx.x;
  const int lane = tid & 63, wid = tid >> 6;
  const int l15 = lane & 15, lk = lane >> 4;
  const int swzh = (l15 & 7) << 3;           // row = ct*16+l15 -> row&7 = l15&7
  const long long grow = (long long)blockIdx.x * 128 + wid * 16 + l15;

  // ---- stage weights L2 -> LDS (linear, conflict-free; overlaps PE below) ----
  for (int i = tid * 8; i < LIMG; i += 4096)
    *(float4*)(wlds + i) = *(const float4*)(ws + i);

  // ---- PE + policy-1 (registers only) ----
  float4 xv = ((const float4*)x)[grow];
  f16x4 h0q[4], f1q[2];
  {
    const float4* pe4 = (const float4*)pe_w;
    const float4* p14 = (const float4*)p1_w;
    #pragma unroll
    for (int c = 0; c < 2; ++c)
      #pragma unroll
      for (int i = 0; i < 4; ++i){
        int d = c * 16 + lk * 4 + i;
        float4 w = pe4[d];
        float u = fmaf(xv.x,w.x,fmaf(xv.y,w.y,fmaf(xv.z,w.z,fmaf(xv.w,w.w,pe_b[d]))));
        h0q[c][i]     = (f16)fsin(u);
        h0q[2 + c][i] = (f16)fcos(u);
        float4 wp = p14[d];
        float z = 30.f*fmaf(xv.x,wp.x,fmaf(xv.y,wp.y,fmaf(xv.z,wp.z,fmaf(xv.w,wp.w,p1_b[d]))));
        f1q[c][i] = (f16)fsin(z);
      }
  }

  // ---- policy-2 (weights from L2, kappa-permuted, 30/2pi folded) ----
  f16x4 f2q[2];
  {
    f16x8 bfp = __builtin_shufflevector(f1q[0], f1q[1], 0,1,2,3,4,5,6,7);
    #pragma unroll
    for (int ct = 0; ct < 2; ++ct){
      float4 b4 = *(const float4*)(bws + FB_P2 + ct * 16 + lk * 4);
      f32x4 acc = {b4.x, b4.y, b4.z, b4.w};
      f16x8 wv = *(const f16x8*)(ws + OFF_WP2 + (ct * 16 + l15) * 32 + 8 * lk);
      acc = __builtin_amdgcn_mfma_f32_16x16x32_f16(wv, bfp, acc, 0, 0, 0);
      f2q[ct] = sin4p(acc);
    }
  }

  __syncthreads();   // the ONLY barrier: weights staged

  // ---- SIREN + bottleneck chain, all in registers ----
  f16x4 h1q[8];
  LAYER_LDS(8, 2, L_W1, FB_B1, h0q, h1q[ct] = sin4p(acc))
  f16x4 h2s[16];
  LAYER_LDS(16, 4, L_W2, FB_B2, h1q, h2s[ct] = sin4p(acc))
  f16x4 t1q[4];
  LAYER_LDS(4, 8, L_WF1, FB_F1, h2s, t1q[ct] = relu4(acc))
  f16x4 t2q[4];
  LAYER_LDS(4, 2, L_WF2, FB_F2, t1q, t2q[ct] = relu4(acc))
  // fc3 + residual in place: h2s <- relu(t2q@W3 + h2s)  (becomes gate input)
  LAYER_LDS(16, 2, L_WF3, FB_F3, t2q, h2s[ct] = resrelu4(acc, h2s[ct]))

  // ---- gate + experts (swapped) + in-wave softmax/routing ----
  {
    float4 gb = ((const float4*)(bws + FB_GE))[lk];
    f32x4 acc = {gb.x, gb.y, gb.z, gb.w};
    #pragma unroll
    for (int ks = 0; ks < 8; ++ks){
      f16x8 wv = *(const f16x8*)(ws + OFF_WGE + l15 * 288 + 32 * ks + 8 * lk);
      f16x8 bf = __builtin_shufflevector(h2s[2*ks], h2s[2*ks+1], 0,1,2,3,4,5,6,7);
      acc = __builtin_amdgcn_mfma_f32_16x16x32_f16(wv, bf, acc, 0, 0, 0);
    }
    {
      f16x8 wv = *(const f16x8*)(ws + OFF_WGE + l15 * 288 + 256 + 8 * lk);
      f16x8 bf = __builtin_shufflevector(f2q[0], f2q[1], 0,1,2,3,4,5,6,7);
      acc = __builtin_amdgcn_mfma_f32_16x16x32_f16(wv, bf, acc, 0, 0, 0);
    }
    // lane (l15,lk) holds gate rows m=4lk+i for batch row l15:
    // lk=0,1 -> logits 0..7 (7=pad), lk=2,3 -> preds 8..15.
    float pred[4], lg[4];
    #pragma unroll
    for (int i = 0; i < 4; ++i) pred[i] = __shfl_xor(acc[i], 32);
    #pragma unroll
    for (int i = 0; i < 4; ++i) lg[i] = acc[i];
    if (lk == 1) lg[3] = -1e30f;               // gate row 7 = padding
    float mx = fmaxf(fmaxf(lg[0], lg[1]), fmaxf(lg[2], lg[3]));
    mx = fmaxf(mx, __shfl_xor(mx, 16));
    float s = 0.f, y = 0.f;
    #pragma unroll
    for (int i = 0; i < 4; ++i){ float p = __expf(lg[i] - mx); s += p; y += p * pred[i]; }
    s += __shfl_xor(s, 16); y += __shfl_xor(y, 16);
    if (lk == 0) out[grow] = y / s;
  }
}

extern "C" void kernel_launch(void* const* d_in, const int* in_sizes, int n_in,
                              void* d_out, int out_size, void* d_ws, size_t ws_size,
                              hipStream_t stream)
{
  const float* x     = (const float*)d_in[0];
  const float* pe_w  = (const float*)d_in[1];
  const float* pe_b  = (const float*)d_in[2];
  const float* s1_w  = (const float*)d_in[3];
  const float* s1_b  = (const float*)d_in[4];
  const float* s2_w  = (const float*)d_in[5];
  const float* s2_b  = (const float*)d_in[6];
  const float* fc1_w = (const float*)d_in[7];
  const float* fc1_b = (const float*)d_in[8];
  const float* fc2_w = (const float*)d_in[9];
  const float* fc2_b = (const float*)d_in[10];
  const float* fc3_w = (const float*)d_in[11];
  const float* fc3_b = (const float*)d_in[12];
  const float* p1_w  = (const float*)d_in[13];
  const float* p1_b  = (const float*)d_in[14];
  const float* p2_w  = (const float*)d_in[15];
  const float* p2_b  = (const float*)d_in[16];
  const float* gate_w= (const float*)d_in[17];
  const float* gate_b= (const float*)d_in[18];
  const float* exp_w = (const float*)d_in[19];
  const float* exp_b = (const float*)d_in[20];
  f16* ws = (f16*)d_ws;

  convert_w<<<128, 256, 0, stream>>>(s1_w, s1_b, s2_w, s2_b, fc1_w, fc1_b, fc2_w, fc2_b,
                                     fc3_w, fc3_b, gate_w, gate_b, exp_w, exp_b, p2_w, p2_b, ws);
  moe_main<<<524288 / 128, 512, 0, stream>>>(x, pe_w, pe_b, p1_w, p1_b, ws, (float*)d_out);
}

// Round 10
// 151.285 us; speedup vs baseline: 3.0712x; 1.2140x over previous
//
#include <hip/hip_runtime.h>

typedef _Float16 f16;
typedef _Float16 f16x4 __attribute__((ext_vector_type(4)));
typedef _Float16 f16x8 __attribute__((ext_vector_type(8)));
typedef float f32x4 __attribute__((ext_vector_type(4)));

// ---- f16 weight arena in d_ws (units: halfs) ----
// [0, 77824): LDS image, kappa-permuted + XOR-swizzled, row-major:
#define L_W1   0             // s1_w *30/2pi   [128][64]
#define L_W2   8192          // s2_w *30/2pi   [256][128]
#define L_WF1  40960         // fc1_w          [64][256]
#define L_WF2  57344         // fc2_w          [64][64]
#define L_WF3  61440         // fc3_w          [256][64]
#define LIMG   77824         // LDS image halfs (155648 B)
#define OFF_WGE 77824        // [16][288] kappa-permuted (no swz): rows 0-6 gate, 8-14 experts
#define OFF_WP2 82432        // p2_w *30/2pi  [32][32] kappa-permuted (no swz)
#define TOTH    83456
// ---- fp32 arena at (float*)(ws + TOTH) ----
#define FB_B1  0
#define FB_B2  128
#define FB_F1  384
#define FB_F2  448
#define FB_F3  512
#define FB_GE  768           // gate_b(0..6), 0, exp_b(8..14), 0
#define FB_P2  784
#define FB_PEW 816           // pe_w * 1/2pi   [32][4]
#define FB_PEB 944           // pe_b * 1/2pi   [32]
#define FB_P1W 976           // p1_w * 30/2pi  [32][4]
#define FB_P1B 1104          // p1_b * 30/2pi  [32]
#define FBTOT  1136

#define SIREN_SCL 4.77464829275686f   // 30/(2*pi)
#define INV2PI    0.15915494309189535f

// input in revolutions; v_sin is 1-periodic so fract is a full reduction
__device__ __forceinline__ float sin_pre(float v){
  return __builtin_amdgcn_sinf(__builtin_amdgcn_fractf(v));
}

// kappa-permutation: B-operand slot kappa (within a 32-K chunk) <- logical column.
__device__ __forceinline__ int permk(int k){
  return 16 * ((k & 7) >> 2) + ((k >> 3) & 3) * 4 + (k & 3);
}

// ---------- weight conversion: fp32 -> f16, scales folded, perm+swizzle ----------
__global__ void convert_w(const float* __restrict__ s1w, const float* __restrict__ s1b,
                          const float* __restrict__ s2w, const float* __restrict__ s2b,
                          const float* __restrict__ f1w, const float* __restrict__ f1b,
                          const float* __restrict__ f2w, const float* __restrict__ f2b,
                          const float* __restrict__ f3w, const float* __restrict__ f3b,
                          const float* __restrict__ gw,  const float* __restrict__ gb,
                          const float* __restrict__ ew,  const float* __restrict__ eb,
                          const float* __restrict__ p2w, const float* __restrict__ p2b,
                          const float* __restrict__ pew, const float* __restrict__ peb,
                          const float* __restrict__ p1w, const float* __restrict__ p1b,
                          f16* __restrict__ ws)
{
  int stride = gridDim.x * blockDim.x;
  int t0 = blockIdx.x * blockDim.x + threadIdx.x;
  for (int i = t0; i < TOTH; i += stride){
    float v;
    if (i < L_W2){                         // W1 [128][64], swz, *30/2pi
      int r = i >> 6, s = i & 63, k = s ^ ((r & 7) << 3);
      v = SIREN_SCL * s1w[(r << 6) + (k & 32) + permk(k & 31)];
    } else if (i < L_WF1){                 // W2 [256][128], swz, *30/2pi
      int j = i - L_W2, r = j >> 7, s = j & 127, k = s ^ ((r & 7) << 3);
      v = SIREN_SCL * s2w[(r << 7) + (k & 96) + permk(k & 31)];
    } else if (i < L_WF2){                 // WF1 [64][256], swz
      int j = i - L_WF1, r = j >> 8, s = j & 255, k = s ^ ((r & 7) << 3);
      v = f1w[(r << 8) + (k & 224) + permk(k & 31)];
    } else if (i < L_WF3){                 // WF2 [64][64], swz
      int j = i - L_WF2, r = j >> 6, s = j & 63, k = s ^ ((r & 7) << 3);
      v = f2w[(r << 6) + (k & 32) + permk(k & 31)];
    } else if (i < OFF_WGE){               // WF3 [256][64], swz
      int j = i - L_WF3, r = j >> 6, s = j & 63, k = s ^ ((r & 7) << 3);
      v = f3w[(r << 6) + (k & 32) + permk(k & 31)];
    } else if (i < OFF_WP2){               // WGE [16][288], perm only
      int j = i - OFF_WGE, r = j / 288, k = j - r * 288;
      int p = (k & ~31) + permk(k & 31);
      v = (r < 7) ? gw[r * 288 + p]
        : ((r >= 8 && r < 15 && p < 256) ? ew[(r - 8) * 256 + p] : 0.f);
    } else {                               // WP2 [32][32], perm only, *30/2pi
      int j = i - OFF_WP2, r = j >> 5, k = j & 31;
      v = SIREN_SCL * p2w[(r << 5) + permk(k)];
    }
    ws[i] = (f16)v;
  }
  float* bws = (float*)(ws + TOTH);
  for (int i = t0; i < FBTOT; i += stride){
    float v;
    if (i < 128)      v = SIREN_SCL * s1b[i];
    else if (i < 384) v = SIREN_SCL * s2b[i - 128];
    else if (i < 448) v = f1b[i - 384];
    else if (i < 512) v = f2b[i - 448];
    else if (i < 768) v = f3b[i - 512];
    else if (i < 784){ int j = i - 768;
      v = (j < 7) ? gb[j] : ((j >= 8 && j < 15) ? eb[j - 8] : 0.0f); }
    else if (i < 816) v = SIREN_SCL * p2b[i - 784];
    else if (i < 944) v = INV2PI * pew[i - FB_PEW];
    else if (i < 976) v = INV2PI * peb[i - FB_PEB];
    else if (i < 1104) v = SIREN_SCL * p1w[i - FB_P1W];
    else v = SIREN_SCL * p1b[i - FB_P1B];
    bws[i] = v;
  }
}

__device__ __forceinline__ f16x4 sin4p(f32x4 a){   // pre-scaled (revolutions)
  f16x4 o; o[0]=(f16)sin_pre(a[0]); o[1]=(f16)sin_pre(a[1]);
  o[2]=(f16)sin_pre(a[2]); o[3]=(f16)sin_pre(a[3]); return o;
}
__device__ __forceinline__ f16x4 relu4(f32x4 a){
  f16x4 o; o[0]=(f16)fmaxf(a[0],0.f); o[1]=(f16)fmaxf(a[1],0.f);
  o[2]=(f16)fmaxf(a[2],0.f); o[3]=(f16)fmaxf(a[3],0.f); return o;
}
__device__ __forceinline__ f16x4 resrelu4(f32x4 a, f16x4 old){
  f16x4 o;
  o[0]=(f16)fmaxf(a[0]+(float)old[0],0.f); o[1]=(f16)fmaxf(a[1]+(float)old[1],0.f);
  o[2]=(f16)fmaxf(a[2]+(float)old[2],0.f); o[3]=(f16)fmaxf(a[3]+(float)old[3],0.f);
  return o;
}

// In-register layer, 2 row-groups: each LDS weight fragment feeds 2 independent
// MFMA chains (g=0,1) -> LDS traffic per row halved vs R9. OUTSTMT sees ct, g, acc[g].
#define LAYER_LDS(NT_, NKS_, LOFF_, BOFF_, INq_, OUTSTMT_)                        \
  _Pragma("unroll")                                                               \
  for (int ct = 0; ct < (NT_); ++ct){                                             \
    float4 b4 = *(const float4*)(bws + (BOFF_) + ct * 16 + lk * 4);               \
    f32x4 acc[2];                                                                 \
    acc[0] = (f32x4){b4.x, b4.y, b4.z, b4.w};  acc[1] = acc[0];                   \
    _Pragma("unroll")                                                             \
    for (int ks = 0; ks < (NKS_); ++ks){                                          \
      f16x8 wv = *(const f16x8*)(wlds + (LOFF_) + (ct * 16 + l15) * ((NKS_) * 32) \
                                  + ((32 * ks + 8 * lk) ^ swzh));                 \
      _Pragma("unroll")                                                           \
      for (int g = 0; g < 2; ++g){                                                \
        f16x8 bf = __builtin_shufflevector((INq_)[g][2 * ks], (INq_)[g][2 * ks + 1], \
                                           0, 1, 2, 3, 4, 5, 6, 7);               \
        acc[g] = __builtin_amdgcn_mfma_f32_16x16x32_f16(wv, bf, acc[g], 0, 0, 0); \
      }                                                                           \
    }                                                                             \
    _Pragma("unroll")                                                             \
    for (int g = 0; g < 2; ++g){ OUTSTMT_; }                                      \
  }

__global__ __launch_bounds__(512, 2) void moe_main(
    const float* __restrict__ x,
    const f16* __restrict__ ws, float* __restrict__ out)
{
  const float* bws = (const float*)(ws + TOTH);
  __shared__ __align__(16) f16 wlds[LIMG];   // 155648 B -> 1 block/CU, 8 waves

  const int tid = threadIdx.x;
  const int lane = tid & 63, wid = tid >> 6;
  const int l15 = lane & 15, lk = lane >> 4;
  const int swzh = (l15 & 7) << 3;           // row = ct*16+l15 -> row&7 = l15&7
  // wave owns 32 rows: g=0 -> +l15, g=1 -> +16+l15
  const long long grow0 = (long long)blockIdx.x * 256 + wid * 32 + l15;

  // ---- stage weights L2 -> LDS (linear, conflict-free; overlaps PE below) ----
  for (int i = tid * 8; i < LIMG; i += 4096)
    *(float4*)(wlds + i) = *(const float4*)(ws + i);

  // ---- PE + policy-1 (registers only; pe/p1 pre-scaled to revolutions) ----
  float4 xv[2];
  xv[0] = ((const float4*)x)[grow0];
  xv[1] = ((const float4*)x)[grow0 + 16];
  f16x4 h0q[2][4], f1q[2][2];
  {
    const float4* pe4 = (const float4*)(bws + FB_PEW);
    const float4* p14 = (const float4*)(bws + FB_P1W);
    #pragma unroll
    for (int c = 0; c < 2; ++c)
      #pragma unroll
      for (int i = 0; i < 4; ++i){
        int d = c * 16 + lk * 4 + i;
        float4 w  = pe4[d]; float wb = bws[FB_PEB + d];
        float4 wp = p14[d]; float pb = bws[FB_P1B + d];
        #pragma unroll
        for (int g = 0; g < 2; ++g){
          float u = fmaf(xv[g].x,w.x,fmaf(xv[g].y,w.y,fmaf(xv[g].z,w.z,fmaf(xv[g].w,w.w,wb))));
          h0q[g][c][i]     = (f16)sin_pre(u);
          h0q[g][2 + c][i] = (f16)sin_pre(u + 0.25f);   // cos
          float z = fmaf(xv[g].x,wp.x,fmaf(xv[g].y,wp.y,fmaf(xv[g].z,wp.z,fmaf(xv[g].w,wp.w,pb))));
          f1q[g][c][i] = (f16)sin_pre(z);
        }
      }
  }

  // ---- policy-2 (weights from L2, kappa-permuted, 30/2pi folded) ----
  f16x4 f2q[2][2];
  {
    #pragma unroll
    for (int ct = 0; ct < 2; ++ct){
      float4 b4 = *(const float4*)(bws + FB_P2 + ct * 16 + lk * 4);
      f16x8 wv = *(const f16x8*)(ws + OFF_WP2 + (ct * 16 + l15) * 32 + 8 * lk);
      #pragma unroll
      for (int g = 0; g < 2; ++g){
        f16x8 bfp = __builtin_shufflevector(f1q[g][0], f1q[g][1], 0,1,2,3,4,5,6,7);
        f32x4 acc = {b4.x, b4.y, b4.z, b4.w};
        acc = __builtin_amdgcn_mfma_f32_16x16x32_f16(wv, bfp, acc, 0, 0, 0);
        f2q[g][ct] = sin4p(acc);
      }
    }
  }

  __syncthreads();   // the ONLY barrier: weights staged

  // ---- SIREN + bottleneck chain, all in registers ----
  f16x4 h1q[2][8];
  LAYER_LDS(8, 2, L_W1, FB_B1, h0q, h1q[g][ct] = sin4p(acc[g]))
  f16x4 h2s[2][16];
  LAYER_LDS(16, 4, L_W2, FB_B2, h1q, h2s[g][ct] = sin4p(acc[g]))
  f16x4 t1q[2][4];
  LAYER_LDS(4, 8, L_WF1, FB_F1, h2s, t1q[g][ct] = relu4(acc[g]))
  f16x4 t2q[2][4];
  LAYER_LDS(4, 2, L_WF2, FB_F2, t1q, t2q[g][ct] = relu4(acc[g]))
  // fc3 + residual in place: h2s <- relu(t2q@W3 + h2s)  (becomes gate input)
  LAYER_LDS(16, 2, L_WF3, FB_F3, t2q, h2s[g][ct] = resrelu4(acc[g], h2s[g][ct]))

  // ---- gate + experts (swapped) + in-wave softmax/routing, per group ----
  {
    float4 gb = ((const float4*)(bws + FB_GE))[lk];
    #pragma unroll
    for (int g = 0; g < 2; ++g){
      f32x4 acc = {gb.x, gb.y, gb.z, gb.w};
      #pragma unroll
      for (int ks = 0; ks < 8; ++ks){
        f16x8 wv = *(const f16x8*)(ws + OFF_WGE + l15 * 288 + 32 * ks + 8 * lk);
        f16x8 bf = __builtin_shufflevector(h2s[g][2*ks], h2s[g][2*ks+1], 0,1,2,3,4,5,6,7);
        acc = __builtin_amdgcn_mfma_f32_16x16x32_f16(wv, bf, acc, 0, 0, 0);
      }
      {
        f16x8 wv = *(const f16x8*)(ws + OFF_WGE + l15 * 288 + 256 + 8 * lk);
        f16x8 bf = __builtin_shufflevector(f2q[g][0], f2q[g][1], 0,1,2,3,4,5,6,7);
        acc = __builtin_amdgcn_mfma_f32_16x16x32_f16(wv, bf, acc, 0, 0, 0);
      }
      // lane (l15,lk): gate rows m=4lk+i for batch row l15; lk<2 logits, lk>=2 preds
      float pred[4], lg[4];
      #pragma unroll
      for (int i = 0; i < 4; ++i) pred[i] = __shfl_xor(acc[i], 32);
      #pragma unroll
      for (int i = 0; i < 4; ++i) lg[i] = acc[i];
      if (lk == 1) lg[3] = -1e30f;             // gate row 7 = padding
      float mx = fmaxf(fmaxf(lg[0], lg[1]), fmaxf(lg[2], lg[3]));
      mx = fmaxf(mx, __shfl_xor(mx, 16));
      float s = 0.f, y = 0.f;
      #pragma unroll
      for (int i = 0; i < 4; ++i){ float p = __expf(lg[i] - mx); s += p; y += p * pred[i]; }
      s += __shfl_xor(s, 16); y += __shfl_xor(y, 16);
      if (lk == 0) out[grow0 + g * 16] = y / s;
    }
  }
}

extern "C" void kernel_launch(void* const* d_in, const int* in_sizes, int n_in,
                              void* d_out, int out_size, void* d_ws, size_t ws_size,
                              hipStream_t stream)
{
  const float* x     = (const float*)d_in[0];
  const float* pe_w  = (const float*)d_in[1];
  const float* pe_b  = (const float*)d_in[2];
  const float* s1_w  = (const float*)d_in[3];
  const float* s1_b  = (const float*)d_in[4];
  const float* s2_w  = (const float*)d_in[5];
  const float* s2_b  = (const float*)d_in[6];
  const float* fc1_w = (const float*)d_in[7];
  const float* fc1_b = (const float*)d_in[8];
  const float* fc2_w = (const float*)d_in[9];
  const float* fc2_b = (const float*)d_in[10];
  const float* fc3_w = (const float*)d_in[11];
  const float* fc3_b = (const float*)d_in[12];
  const float* p1_w  = (const float*)d_in[13];
  const float* p1_b  = (const float*)d_in[14];
  const float* p2_w  = (const float*)d_in[15];
  const float* p2_b  = (const float*)d_in[16];
  const float* gate_w= (const float*)d_in[17];
  const float* gate_b= (const float*)d_in[18];
  const float* exp_w = (const float*)d_in[19];
  const float* exp_b = (const float*)d_in[20];
  f16* ws = (f16*)d_ws;

  convert_w<<<128, 256, 0, stream>>>(s1_w, s1_b, s2_w, s2_b, fc1_w, fc1_b, fc2_w, fc2_b,
                                     fc3_w, fc3_b, gate_w, gate_b, exp_w, exp_b, p2_w, p2_b,
                                     pe_w, pe_b, p1_w, p1_b, ws);
  moe_main<<<524288 / 256, 512, 0, stream>>>(x, ws, (float*)d_out);
}

// Round 11
// 151.076 us; speedup vs baseline: 3.0755x; 1.0014x over previous
//
#include <hip/hip_runtime.h>

typedef _Float16 f16;
typedef _Float16 f16x4 __attribute__((ext_vector_type(4)));
typedef _Float16 f16x8 __attribute__((ext_vector_type(8)));
typedef float f32x4 __attribute__((ext_vector_type(4)));

// ---- f16 weight arena in d_ws (units: halfs) ----
// [0, 77824): LDS image, kappa-permuted + XOR-swizzled, row-major:
#define L_W1   0             // s1_w *30/2pi   [128][64]
#define L_W2   8192          // s2_w *30/2pi   [256][128]
#define L_WF1  40960         // fc1_w          [64][256]
#define L_WF2  57344         // fc2_w          [64][64]
#define L_WF3  61440         // fc3_w          [256][64]
#define LIMG   77824         // LDS image halfs (155648 B)
#define OFF_WGE 77824        // [16][288] kappa-permuted (no swz): rows 0-6 gate, 8-14 experts
#define OFF_WP2 82432        // p2_w *30/2pi  [32][32] kappa-permuted (no swz)
#define TOTH    83456
// ---- fp32 arena at (float*)(ws + TOTH) ----
#define FB_B1  0
#define FB_B2  128
#define FB_F1  384
#define FB_F2  448
#define FB_F3  512
#define FB_GE  768           // gate_b(0..6), 0, exp_b(8..14), 0
#define FB_P2  784
#define FB_PEW 816           // pe_w * 1/2pi   [32][4]
#define FB_PEB 944           // pe_b * 1/2pi   [32]
#define FB_P1W 976           // p1_w * 30/2pi  [32][4]
#define FB_P1B 1104          // p1_b * 30/2pi  [32]
#define FBTOT  1136

#define SIREN_SCL 4.77464829275686f   // 30/(2*pi)
#define INV2PI    0.15915494309189535f

// input in revolutions; v_sin is 1-periodic so fract is a full reduction
__device__ __forceinline__ float sin_pre(float v){
  return __builtin_amdgcn_sinf(__builtin_amdgcn_fractf(v));
}

// kappa-permutation: B-operand slot kappa (within a 32-K chunk) <- logical column.
__device__ __forceinline__ int permk(int k){
  return 16 * ((k & 7) >> 2) + ((k >> 3) & 3) * 4 + (k & 3);
}

// ---------- weight conversion: fp32 -> f16, scales folded, perm+swizzle ----------
__global__ void convert_w(const float* __restrict__ s1w, const float* __restrict__ s1b,
                          const float* __restrict__ s2w, const float* __restrict__ s2b,
                          const float* __restrict__ f1w, const float* __restrict__ f1b,
                          const float* __restrict__ f2w, const float* __restrict__ f2b,
                          const float* __restrict__ f3w, const float* __restrict__ f3b,
                          const float* __restrict__ gw,  const float* __restrict__ gb,
                          const float* __restrict__ ew,  const float* __restrict__ eb,
                          const float* __restrict__ p2w, const float* __restrict__ p2b,
                          const float* __restrict__ pew, const float* __restrict__ peb,
                          const float* __restrict__ p1w, const float* __restrict__ p1b,
                          f16* __restrict__ ws)
{
  int stride = gridDim.x * blockDim.x;
  int t0 = blockIdx.x * blockDim.x + threadIdx.x;
  for (int i = t0; i < TOTH; i += stride){
    float v;
    if (i < L_W2){                         // W1 [128][64], swz, *30/2pi
      int r = i >> 6, s = i & 63, k = s ^ ((r & 7) << 3);
      v = SIREN_SCL * s1w[(r << 6) + (k & 32) + permk(k & 31)];
    } else if (i < L_WF1){                 // W2 [256][128], swz, *30/2pi
      int j = i - L_W2, r = j >> 7, s = j & 127, k = s ^ ((r & 7) << 3);
      v = SIREN_SCL * s2w[(r << 7) + (k & 96) + permk(k & 31)];
    } else if (i < L_WF2){                 // WF1 [64][256], swz
      int j = i - L_WF1, r = j >> 8, s = j & 255, k = s ^ ((r & 7) << 3);
      v = f1w[(r << 8) + (k & 224) + permk(k & 31)];
    } else if (i < L_WF3){                 // WF2 [64][64], swz
      int j = i - L_WF2, r = j >> 6, s = j & 63, k = s ^ ((r & 7) << 3);
      v = f2w[(r << 6) + (k & 32) + permk(k & 31)];
    } else if (i < OFF_WGE){               // WF3 [256][64], swz
      int j = i - L_WF3, r = j >> 6, s = j & 63, k = s ^ ((r & 7) << 3);
      v = f3w[(r << 6) + (k & 32) + permk(k & 31)];
    } else if (i < OFF_WP2){               // WGE [16][288], perm only
      int j = i - OFF_WGE, r = j / 288, k = j - r * 288;
      int p = (k & ~31) + permk(k & 31);
      v = (r < 7) ? gw[r * 288 + p]
        : ((r >= 8 && r < 15 && p < 256) ? ew[(r - 8) * 256 + p] : 0.f);
    } else {                               // WP2 [32][32], perm only, *30/2pi
      int j = i - OFF_WP2, r = j >> 5, k = j & 31;
      v = SIREN_SCL * p2w[(r << 5) + permk(k)];
    }
    ws[i] = (f16)v;
  }
  float* bws = (float*)(ws + TOTH);
  for (int i = t0; i < FBTOT; i += stride){
    float v;
    if (i < 128)      v = SIREN_SCL * s1b[i];
    else if (i < 384) v = SIREN_SCL * s2b[i - 128];
    else if (i < 448) v = f1b[i - 384];
    else if (i < 512) v = f2b[i - 448];
    else if (i < 768) v = f3b[i - 512];
    else if (i < 784){ int j = i - 768;
      v = (j < 7) ? gb[j] : ((j >= 8 && j < 15) ? eb[j - 8] : 0.0f); }
    else if (i < 816) v = SIREN_SCL * p2b[i - 784];
    else if (i < 944) v = INV2PI * pew[i - FB_PEW];
    else if (i < 976) v = INV2PI * peb[i - FB_PEB];
    else if (i < 1104) v = SIREN_SCL * p1w[i - FB_P1W];
    else v = SIREN_SCL * p1b[i - FB_P1B];
    bws[i] = v;
  }
}

__device__ __forceinline__ f16x4 sin4p(f32x4 a){   // pre-scaled (revolutions)
  f16x4 o; o[0]=(f16)sin_pre(a[0]); o[1]=(f16)sin_pre(a[1]);
  o[2]=(f16)sin_pre(a[2]); o[3]=(f16)sin_pre(a[3]); return o;
}
__device__ __forceinline__ f16x4 relu4(f32x4 a){
  f16x4 o; o[0]=(f16)fmaxf(a[0],0.f); o[1]=(f16)fmaxf(a[1],0.f);
  o[2]=(f16)fmaxf(a[2],0.f); o[3]=(f16)fmaxf(a[3],0.f); return o;
}
__device__ __forceinline__ f16x4 resrelu4(f32x4 a, f16x4 old){
  f16x4 o;
  o[0]=(f16)fmaxf(a[0]+(float)old[0],0.f); o[1]=(f16)fmaxf(a[1]+(float)old[1],0.f);
  o[2]=(f16)fmaxf(a[2]+(float)old[2],0.f); o[3]=(f16)fmaxf(a[3]+(float)old[3],0.f);
  return o;
}

// In-register layer, 2 row-groups: each LDS weight fragment feeds 2 independent
// MFMA chains (g=0,1) -> LDS traffic per row halved vs R9. OUTSTMT sees ct, g, acc[g].
#define LAYER_LDS(NT_, NKS_, LOFF_, BOFF_, INq_, OUTSTMT_)                        \
  _Pragma("unroll")                                                               \
  for (int ct = 0; ct < (NT_); ++ct){                                             \
    float4 b4 = *(const float4*)(bws + (BOFF_) + ct * 16 + lk * 4);               \
    f32x4 acc[2];                                                                 \
    acc[0] = (f32x4){b4.x, b4.y, b4.z, b4.w};  acc[1] = acc[0];                   \
    _Pragma("unroll")                                                             \
    for (int ks = 0; ks < (NKS_); ++ks){                                          \
      f16x8 wv = *(const f16x8*)(wlds + (LOFF_) + (ct * 16 + l15) * ((NKS_) * 32) \
                                  + ((32 * ks + 8 * lk) ^ swzh));                 \
      _Pragma("unroll")                                                           \
      for (int g = 0; g < 2; ++g){                                                \
        f16x8 bf = __builtin_shufflevector((INq_)[g][2 * ks], (INq_)[g][2 * ks + 1], \
                                           0, 1, 2, 3, 4, 5, 6, 7);               \
        acc[g] = __builtin_amdgcn_mfma_f32_16x16x32_f16(wv, bf, acc[g], 0, 0, 0); \
      }                                                                           \
    }                                                                             \
    _Pragma("unroll")                                                             \
    for (int g = 0; g < 2; ++g){ OUTSTMT_; }                                      \
  }

// waves_per_eu(2,2): LDS (152KB) caps the CU at one 8-wave block = 2 waves/SIMD.
// R10's default heuristic targeted 4 waves/SIMD (128 VGPRs) -> 78MB spill for
// phantom occupancy. Pinning min=max=2 unlocks the full 256-VGPR budget.
__global__ __launch_bounds__(512)
__attribute__((amdgpu_waves_per_eu(2, 2)))
void moe_main(
    const float* __restrict__ x,
    const f16* __restrict__ ws, float* __restrict__ out)
{
  const float* bws = (const float*)(ws + TOTH);
  __shared__ __align__(16) f16 wlds[LIMG];   // 155648 B -> 1 block/CU, 8 waves

  const int tid = threadIdx.x;
  const int lane = tid & 63, wid = tid >> 6;
  const int l15 = lane & 15, lk = lane >> 4;
  const int swzh = (l15 & 7) << 3;           // row = ct*16+l15 -> row&7 = l15&7
  // wave owns 32 rows: g=0 -> +l15, g=1 -> +16+l15
  const long long grow0 = (long long)blockIdx.x * 256 + wid * 32 + l15;

  // ---- stage weights L2 -> LDS (linear, conflict-free; overlaps PE below) ----
  for (int i = tid * 8; i < LIMG; i += 4096)
    *(float4*)(wlds + i) = *(const float4*)(ws + i);

  // ---- PE + policy-1 (registers only; pe/p1 pre-scaled to revolutions) ----
  float4 xv[2];
  xv[0] = ((const float4*)x)[grow0];
  xv[1] = ((const float4*)x)[grow0 + 16];
  f16x4 h0q[2][4], f1q[2][2];
  {
    const float4* pe4 = (const float4*)(bws + FB_PEW);
    const float4* p14 = (const float4*)(bws + FB_P1W);
    #pragma unroll
    for (int c = 0; c < 2; ++c)
      #pragma unroll
      for (int i = 0; i < 4; ++i){
        int d = c * 16 + lk * 4 + i;
        float4 w  = pe4[d]; float wb = bws[FB_PEB + d];
        float4 wp = p14[d]; float pb = bws[FB_P1B + d];
        #pragma unroll
        for (int g = 0; g < 2; ++g){
          float u = fmaf(xv[g].x,w.x,fmaf(xv[g].y,w.y,fmaf(xv[g].z,w.z,fmaf(xv[g].w,w.w,wb))));
          h0q[g][c][i]     = (f16)sin_pre(u);
          h0q[g][2 + c][i] = (f16)sin_pre(u + 0.25f);   // cos
          float z = fmaf(xv[g].x,wp.x,fmaf(xv[g].y,wp.y,fmaf(xv[g].z,wp.z,fmaf(xv[g].w,wp.w,pb))));
          f1q[g][c][i] = (f16)sin_pre(z);
        }
      }
  }

  // ---- policy-2 (weights from L2, kappa-permuted, 30/2pi folded) ----
  f16x4 f2q[2][2];
  {
    #pragma unroll
    for (int ct = 0; ct < 2; ++ct){
      float4 b4 = *(const float4*)(bws + FB_P2 + ct * 16 + lk * 4);
      f16x8 wv = *(const f16x8*)(ws + OFF_WP2 + (ct * 16 + l15) * 32 + 8 * lk);
      #pragma unroll
      for (int g = 0; g < 2; ++g){
        f16x8 bfp = __builtin_shufflevector(f1q[g][0], f1q[g][1], 0,1,2,3,4,5,6,7);
        f32x4 acc = {b4.x, b4.y, b4.z, b4.w};
        acc = __builtin_amdgcn_mfma_f32_16x16x32_f16(wv, bfp, acc, 0, 0, 0);
        f2q[g][ct] = sin4p(acc);
      }
    }
  }

  __syncthreads();   // the ONLY barrier: weights staged

  // ---- SIREN + bottleneck chain, all in registers ----
  f16x4 h1q[2][8];
  LAYER_LDS(8, 2, L_W1, FB_B1, h0q, h1q[g][ct] = sin4p(acc[g]))
  f16x4 h2s[2][16];
  LAYER_LDS(16, 4, L_W2, FB_B2, h1q, h2s[g][ct] = sin4p(acc[g]))
  f16x4 t1q[2][4];
  LAYER_LDS(4, 8, L_WF1, FB_F1, h2s, t1q[g][ct] = relu4(acc[g]))
  f16x4 t2q[2][4];
  LAYER_LDS(4, 2, L_WF2, FB_F2, t1q, t2q[g][ct] = relu4(acc[g]))
  // fc3 + residual in place: h2s <- relu(t2q@W3 + h2s)  (becomes gate input)
  LAYER_LDS(16, 2, L_WF3, FB_F3, t2q, h2s[g][ct] = resrelu4(acc[g], h2s[g][ct]))

  // ---- gate + experts (swapped) + in-wave softmax/routing, per group ----
  {
    float4 gb = ((const float4*)(bws + FB_GE))[lk];
    #pragma unroll
    for (int g = 0; g < 2; ++g){
      f32x4 acc = {gb.x, gb.y, gb.z, gb.w};
      #pragma unroll
      for (int ks = 0; ks < 8; ++ks){
        f16x8 wv = *(const f16x8*)(ws + OFF_WGE + l15 * 288 + 32 * ks + 8 * lk);
        f16x8 bf = __builtin_shufflevector(h2s[g][2*ks], h2s[g][2*ks+1], 0,1,2,3,4,5,6,7);
        acc = __builtin_amdgcn_mfma_f32_16x16x32_f16(wv, bf, acc, 0, 0, 0);
      }
      {
        f16x8 wv = *(const f16x8*)(ws + OFF_WGE + l15 * 288 + 256 + 8 * lk);
        f16x8 bf = __builtin_shufflevector(f2q[g][0], f2q[g][1], 0,1,2,3,4,5,6,7);
        acc = __builtin_amdgcn_mfma_f32_16x16x32_f16(wv, bf, acc, 0, 0, 0);
      }
      // lane (l15,lk): gate rows m=4lk+i for batch row l15; lk<2 logits, lk>=2 preds
      float pred[4], lg[4];
      #pragma unroll
      for (int i = 0; i < 4; ++i) pred[i] = __shfl_xor(acc[i], 32);
      #pragma unroll
      for (int i = 0; i < 4; ++i) lg[i] = acc[i];
      if (lk == 1) lg[3] = -1e30f;             // gate row 7 = padding
      float mx = fmaxf(fmaxf(lg[0], lg[1]), fmaxf(lg[2], lg[3]));
      mx = fmaxf(mx, __shfl_xor(mx, 16));
      float s = 0.f, y = 0.f;
      #pragma unroll
      for (int i = 0; i < 4; ++i){ float p = __expf(lg[i] - mx); s += p; y += p * pred[i]; }
      s += __shfl_xor(s, 16); y += __shfl_xor(y, 16);
      if (lk == 0) out[grow0 + g * 16] = y / s;
    }
  }
}

extern "C" void kernel_launch(void* const* d_in, const int* in_sizes, int n_in,
                              void* d_out, int out_size, void* d_ws, size_t ws_size,
                              hipStream_t stream)
{
  const float* x     = (const float*)d_in[0];
  const float* pe_w  = (const float*)d_in[1];
  const float* pe_b  = (const float*)d_in[2];
  const float* s1_w  = (const float*)d_in[3];
  const float* s1_b  = (const float*)d_in[4];
  const float* s2_w  = (const float*)d_in[5];
  const float* s2_b  = (const float*)d_in[6];
  const float* fc1_w = (const float*)d_in[7];
  const float* fc1_b = (const float*)d_in[8];
  const float* fc2_w = (const float*)d_in[9];
  const float* fc2_b = (const float*)d_in[10];
  const float* fc3_w = (const float*)d_in[11];
  const float* fc3_b = (const float*)d_in[12];
  const float* p1_w  = (const float*)d_in[13];
  const float* p1_b  = (const float*)d_in[14];
  const float* p2_w  = (const float*)d_in[15];
  const float* p2_b  = (const float*)d_in[16];
  const float* gate_w= (const float*)d_in[17];
  const float* gate_b= (const float*)d_in[18];
  const float* exp_w = (const float*)d_in[19];
  const float* exp_b = (const float*)d_in[20];
  f16* ws = (f16*)d_ws;

  convert_w<<<128, 256, 0, stream>>>(s1_w, s1_b, s2_w, s2_b, fc1_w, fc1_b, fc2_w, fc2_b,
                                     fc3_w, fc3_b, gate_w, gate_b, exp_w, exp_b, p2_w, p2_b,
                                     pe_w, pe_b, p1_w, p1_b, ws);
  moe_main<<<524288 / 256, 512, 0, stream>>>(x, ws, (float*)d_out);
}